// Round 2
// baseline (314.029 us; speedup 1.0000x reference)
//
#include <hip/hip_runtime.h>

#define IN_DIM 128
#define OUT_DIM 64

// broadcast lane l's value of v to all lanes via v_readlane (VALU pipe, keeps
// the DS pipe free for the W reads)
__device__ __forceinline__ float rdlane(float v, int l) {
    return __int_as_float(__builtin_amdgcn_readlane(__float_as_int(v), l));
}

// ---------------------------------------------------------------------------
// xw = x @ W.  8 rows per wave, lane = output column.  W in LDS k-major:
// wl[k*64+lane] is a stride-1 lane access -> 2-way bank alias (free, m136).
// x rows live in VGPRs; x[r][k] broadcast via v_readlane with unrolled
// (compile-time) lane index.  Per k: 1 ds_read_b32 + 8 readlane + 8 fma
// -> DS-pipe work cut 16x vs R1 (which was LDS-bound at ~120 us).
// ---------------------------------------------------------------------------
__global__ __launch_bounds__(256) void gemm_xw(const float* __restrict__ x,
                                               const float* __restrict__ w,
                                               float* __restrict__ xw, int N) {
    __shared__ float wl[IN_DIM * OUT_DIM];   // 32 KB
    {
        const float4* w4 = (const float4*)w;
        float4* wl4 = (float4*)wl;
        for (int i = threadIdx.x; i < IN_DIM * OUT_DIM / 4; i += 256)
            wl4[i] = w4[i];
    }
    __syncthreads();

    const int lane = threadIdx.x & 63;
    const int gw = (blockIdx.x * 256 + (int)threadIdx.x) >> 6;
    const int r0 = gw * 8;
    if (r0 >= N) return;

    float xr[8][2];
#pragma unroll
    for (int r = 0; r < 8; ++r) {
        int row = r0 + r; if (row >= N) row = N - 1;
        const float* xp = x + (size_t)row * IN_DIM;
        xr[r][0] = xp[lane];          // coalesced 256 B
        xr[r][1] = xp[64 + lane];
    }

    float acc[8] = {0.f, 0.f, 0.f, 0.f, 0.f, 0.f, 0.f, 0.f};
#pragma unroll
    for (int half = 0; half < 2; ++half) {
#pragma unroll
        for (int k = 0; k < 64; ++k) {
            float wv = wl[(half * 64 + k) * OUT_DIM + lane];
#pragma unroll
            for (int r = 0; r < 8; ++r)
                acc[r] = fmaf(rdlane(xr[r][half], k), wv, acc[r]);
        }
    }
#pragma unroll
    for (int r = 0; r < 8; ++r)
        if (r0 + r < N) xw[(size_t)(r0 + r) * OUT_DIM + lane] = acc[r];
}

// ---------------------------------------------------------------------------
// CSR build: histogram -> 3-kernel exclusive scan -> fill (counting sort).
// All atomics here are int adds on a 200 KB L2-resident array.
// ---------------------------------------------------------------------------
__global__ __launch_bounds__(256) void hist_rows(const int* __restrict__ arow,
                                                 int* __restrict__ cnt, int E) {
    int i = blockIdx.x * 256 + threadIdx.x;
    const int stride = gridDim.x * 256;
    for (int e = i; e < E; e += stride) atomicAdd(&cnt[arow[e]], 1);
}

__global__ __launch_bounds__(256) void scan1(const int* __restrict__ cnt,
                                             int* __restrict__ offs,
                                             int* __restrict__ bsum, int n) {
    __shared__ int tmp[256];
    const int t = threadIdx.x;
    const int i = blockIdx.x * 256 + t;
    int v = (i < n) ? cnt[i] : 0;
    tmp[t] = v;
    __syncthreads();
    int run = v;
    for (int s = 1; s < 256; s <<= 1) {
        int a = (t >= s) ? tmp[t - s] : 0;
        __syncthreads();
        run += a;
        tmp[t] = run;
        __syncthreads();
    }
    if (i < n) offs[i] = run - v;                 // block-local exclusive
    if (t == 255) bsum[blockIdx.x] = run;         // block total
}

__global__ __launch_bounds__(256) void scan2(int* __restrict__ bsum, int nb) {
    __shared__ int tmp[256];
    const int t = threadIdx.x;
    int v = (t < nb) ? bsum[t] : 0;
    tmp[t] = v;
    __syncthreads();
    int run = v;
    for (int s = 1; s < 256; s <<= 1) {
        int a = (t >= s) ? tmp[t - s] : 0;
        __syncthreads();
        run += a;
        tmp[t] = run;
        __syncthreads();
    }
    if (t < nb) bsum[t] = run - v;                // exclusive block bases
}

__global__ __launch_bounds__(256) void scan3(int* __restrict__ offs,
                                             int* __restrict__ cur,
                                             const int* __restrict__ bsum,
                                             int n, int E) {
    const int i = blockIdx.x * 256 + threadIdx.x;
    if (i < n) {
        int o = offs[i] + bsum[blockIdx.x];
        offs[i] = o;
        cur[i] = o;
    }
    if (i == 0) offs[n] = E;
}

__global__ __launch_bounds__(256) void fill_csr(const int* __restrict__ arow,
                                                const int* __restrict__ acol,
                                                const float* __restrict__ aval,
                                                int* __restrict__ cur,
                                                float2* __restrict__ payload, int E) {
    int i = blockIdx.x * 256 + threadIdx.x;
    const int stride = gridDim.x * 256;
    for (int e = i; e < E; e += stride) {
        const int r = arow[e];
        const int pos = atomicAdd(&cur[r], 1);
        payload[pos] = make_float2(__int_as_float(acol[e]), aval[e]);
    }
}

// ---------------------------------------------------------------------------
// Pull phase: wave per node, lane = column.  Gathers xw[col] (12.8 MB,
// L2/L3-resident), accumulates in a register, single coalesced 256 B store
// with fused ReLU.  No atomics, no memset, deterministic per-launch.
// ---------------------------------------------------------------------------
__global__ __launch_bounds__(256) void pull_nodes(const int* __restrict__ offs,
                                                  const float2* __restrict__ payload,
                                                  const float* __restrict__ xw,
                                                  float* __restrict__ out, int N) {
    const int lane = threadIdx.x & 63;
    const int r = (blockIdx.x * 256 + (int)threadIdx.x) >> 6;
    if (r >= N) return;
    const int beg = offs[r];
    const int end = offs[r + 1];
    float acc = 0.f;
    for (int j = beg; j < end; ++j) {
        float2 p = payload[j];                     // wave-uniform 8 B
        acc = fmaf(p.y, xw[(size_t)__float_as_int(p.x) * OUT_DIM + lane], acc);
    }
    out[(size_t)r * OUT_DIM + lane] = acc > 0.f ? acc : 0.f;
}

// ---------------------------------------------------------------------------
// Fallback (only if ws_size is too small for the CSR path): R1 atomic scatter.
// ---------------------------------------------------------------------------
__global__ __launch_bounds__(256) void scatter_edges(
        const int* __restrict__ arow, const int* __restrict__ acol,
        const float* __restrict__ aval, const float* __restrict__ xw,
        float* __restrict__ out, int E) {
    const int lane = threadIdx.x & 63;
    int gw = (blockIdx.x * 256 + (int)threadIdx.x) >> 6;
    const int nw = (gridDim.x * 256) >> 6;
    for (int e = gw; e < E; e += nw) {
        const float m = aval[e] * xw[(size_t)acol[e] * OUT_DIM + lane];
        atomicAdd(&out[(size_t)arow[e] * OUT_DIM + lane], m);
    }
}

__global__ __launch_bounds__(256) void relu_inplace(float* __restrict__ o, int n4) {
    float4* p = (float4*)o;
    int i = blockIdx.x * 256 + threadIdx.x;
    const int stride = gridDim.x * 256;
    for (; i < n4; i += stride) {
        float4 v = p[i];
        v.x = v.x > 0.f ? v.x : 0.f;
        v.y = v.y > 0.f ? v.y : 0.f;
        v.z = v.z > 0.f ? v.z : 0.f;
        v.w = v.w > 0.f ? v.w : 0.f;
        p[i] = v;
    }
}

static inline size_t align256(size_t x) { return (x + 255) & ~(size_t)255; }

extern "C" void kernel_launch(void* const* d_in, const int* in_sizes, int n_in,
                              void* d_out, int out_size, void* d_ws, size_t ws_size,
                              hipStream_t stream) {
    const float* x    = (const float*)d_in[0];
    const float* w    = (const float*)d_in[1];
    const int*   arow = (const int*)d_in[2];
    const int*   acol = (const int*)d_in[3];
    const float* aval = (const float*)d_in[4];
    float*       out  = (float*)d_out;

    const int N = in_sizes[0] / IN_DIM;   // 50000
    const int E = in_sizes[2];            // 800000

    // ws layout
    char* ws = (char*)d_ws;
    const size_t szXW   = align256((size_t)N * OUT_DIM * sizeof(float));
    const size_t szOffs = align256((size_t)(N + 1) * sizeof(int));
    const size_t szCur  = align256((size_t)N * sizeof(int));
    const size_t szB    = 1024;
    const size_t szPay  = (size_t)E * sizeof(float2);
    const size_t need   = szXW + szOffs + szCur + szB + szPay;

    float*  xw      = (float*)ws;
    int*    offs    = (int*)(ws + szXW);
    int*    cur     = (int*)(ws + szXW + szOffs);         // also the histogram
    int*    bsum    = (int*)(ws + szXW + szOffs + szCur);
    float2* payload = (float2*)(ws + szXW + szOffs + szCur + szB);

    const int gemm_blocks = (N + 31) / 32;                // 8 rows/wave, 4 waves/blk
    gemm_xw<<<gemm_blocks, 256, 0, stream>>>(x, w, xw, N);

    if (ws_size >= need) {
        const int nb = (N + 255) / 256;                   // 196 (<=256 assumed)
        hipMemsetAsync(cur, 0, (size_t)N * sizeof(int), stream);
        hist_rows<<<800, 256, 0, stream>>>(arow, cur, E);
        scan1<<<nb, 256, 0, stream>>>(cur, offs, bsum, N);
        scan2<<<1, 256, 0, stream>>>(bsum, nb);
        scan3<<<nb, 256, 0, stream>>>(offs, cur, bsum, N, E);
        fill_csr<<<800, 256, 0, stream>>>(arow, acol, aval, cur, payload, E);
        const int pull_blocks = (N + 3) / 4;              // wave per node
        pull_nodes<<<pull_blocks, 256, 0, stream>>>(offs, payload, xw, out, N);
    } else {
        hipMemsetAsync(d_out, 0, (size_t)out_size * sizeof(float), stream);
        scatter_edges<<<4096, 256, 0, stream>>>(arow, acol, aval, xw, out, E);
        relu_inplace<<<2048, 256, 0, stream>>>(out, out_size / 4);
    }
}